// Round 2
// baseline (287.728 us; speedup 1.0000x reference)
//
#include <hip/hip_runtime.h>
#include <math.h>

#define N_TOT   196608      // B*HW*SPP = 4*16384*3
#define HWSPP   49152       // 16384*3
#define RGF     82          // floats per raw gaussian
#define RGS     83          // padded LDS stride
#define NGB     3072        // gauss blocks
#define NFB     1024        // feat blocks

#define OFF_MEANS 0
#define OFF_COV   589824
#define OFF_SH    2359296
#define OFF_OP    17104896
#define OFF_FEAT  17301504
#define OFF_SCL   29884416
#define OFF_ROT   30474240

// workspace float layout: [0,660) D matrices (b*165 + loff[l]); [660,696) Kinv b*9; [696,700) multiplier
__device__ __constant__ int c_loff[5] = {0, 1, 10, 35, 84};

__device__ __forceinline__ float sigmoidf_(float x) { return 1.0f / (1.0f + expf(-x)); }

// ---------------- setup: angles + Wigner D (fp64 expm), ONE WAVE per (b,l) ----------------
__global__ __launch_bounds__(64) void setup_kernel(
    const float* __restrict__ extr, const float* __restrict__ intr,
    const int* __restrict__ img_h, const int* __restrict__ img_w,
    float* __restrict__ ws)
{
  const int b = blockIdx.x / 5;
  const int l = blockIdx.x % 5;
  const int n = 2 * l + 1;
  const int nn = n * n;
  const int t = threadIdx.x;

  __shared__ double Qr[81], Qi[81], X0c[81], X0r[81], X1r[81];
  __shared__ double E[3][81], A_[81], P_[81], T_[81], M1[81];
  __shared__ double ang[3];
  __shared__ int sS;

  if (t == 0) {
    const float* Ex = extr + b * 16;
    double R00 = Ex[0], R01 = Ex[1], R02 = Ex[2];
    double R11 = Ex[5];
    double R20 = Ex[8], R21 = Ex[9], R22 = Ex[10];
    double x0 = R01, x1 = R11, x2 = R21;
    double nr = sqrt(x0 * x0 + x1 * x1 + x2 * x2);
    x0 /= nr; x1 /= nr; x2 /= nr;
    double beta  = acos(fmin(1.0, fmax(-1.0, x1)));
    double alpha = atan2(x0, x2);
    double ca = cos(alpha), sa = sin(alpha);
    double gamma = atan2(ca * R02 - sa * R22, ca * R00 - sa * R20);
    ang[0] = alpha; ang[1] = beta; ang[2] = gamma;
    if (l == 0) {
      const float* K = intr + b * 9;
      double k00=K[0],k01=K[1],k02=K[2],k10=K[3],k11=K[4],k12=K[5],k20=K[6],k21=K[7],k22=K[8];
      double det = k00*(k11*k22-k12*k21) - k01*(k10*k22-k12*k20) + k02*(k10*k21-k11*k20);
      double id = 1.0 / det;
      float* kv = ws + 660 + b * 9;
      kv[0] = (float)((k11*k22-k12*k21)*id);
      kv[1] = (float)((k02*k21-k01*k22)*id);
      kv[2] = (float)((k01*k12-k02*k11)*id);
      kv[3] = (float)((k12*k20-k10*k22)*id);
      kv[4] = (float)((k00*k22-k02*k20)*id);
      kv[5] = (float)((k02*k10-k00*k12)*id);
      kv[6] = (float)((k10*k21-k11*k20)*id);
      kv[7] = (float)((k01*k20-k00*k21)*id);
      kv[8] = (float)((k00*k11-k01*k10)*id);
      double d2 = k00 * k11 - k01 * k10;
      double ps0 = 1.0 / (double)img_w[0];
      double ps1 = 1.0 / (double)img_h[0];
      double sum = (k11 * ps0 - k01 * ps1 - k10 * ps0 + k00 * ps1) / d2;
      ws[696 + b] = (float)(0.1 * sum);
    }
  }
  for (int e = t; e < 81; e += 64) { Qr[e] = 0.0; Qi[e] = 0.0; X0c[e] = 0.0; }
  __syncthreads();
  if (t == 0) {
    const double irt2 = 0.70710678118654752440;
    for (int m = -l; m < 0; ++m) {
      Qr[(l + m) * n + (l - m)] = irt2;      // q[l+m, l+|m|] = 1/sqrt2
      Qi[(l + m) * n + (l + m)] = -irt2;     // q[l+m, l-|m|] = -i/sqrt2
    }
    Qr[l * n + l] = 1.0;
    for (int m = 1; m <= l; ++m) {
      double sg = (m & 1) ? -1.0 : 1.0;
      Qr[(l + m) * n + (l + m)] = sg * irt2; // (-1)^m/sqrt2
      Qi[(l + m) * n + (l - m)] = sg * irt2; // i(-1)^m/sqrt2
    }
    for (int i = 0; i < n - 1; ++i) {        // X0 = 0.5*(raising+lowering)
      double mi = (double)(-l + i);
      double ci = sqrt((double)(l * (l + 1)) - mi * (mi + 1.0));
      X0c[i * n + (i + 1)] = 0.5 * ci;
      X0c[(i + 1) * n + i] = -0.5 * ci;
    }
  }
  __syncthreads();
  for (int e = t; e < nn; e += 64) {  // T = X0c @ Q (A_=Re, P_=Im)
    int i = e / n, j = e % n; double s = 0, s2 = 0;
    for (int k = 0; k < n; ++k) { s += X0c[i*n+k]*Qr[k*n+j]; s2 += X0c[i*n+k]*Qi[k*n+j]; }
    A_[e] = s; P_[e] = s2;
  }
  __syncthreads();
  for (int e = t; e < nn; e += 64) {  // X0r = Re(Q^H T);  X1r = Re(Q^H diag(i m) Q)
    int a = e / n, c = e % n; double s = 0, s1 = 0;
    for (int r = 0; r < n; ++r) {
      s  += Qr[r*n+a]*A_[r*n+c] + Qi[r*n+a]*P_[r*n+c];
      double mr = (double)(r - l);
      s1 += mr * (Qi[r*n+a]*Qr[r*n+c] - Qr[r*n+a]*Qi[r*n+c]);
    }
    X0r[e] = s; X1r[e] = s1;
  }
  __syncthreads();

  // three expm's sequentially: g=0: exp(alpha X1), g=1: exp(-beta X0), g=2: exp(gamma X1)
  for (int g = 0; g < 3; ++g) {
    const double* X = (g == 1) ? X0r : X1r;
    double th = (g == 0) ? ang[0] : ((g == 1) ? -ang[1] : ang[2]);
    if (t == 0) {
      double mx = 0.0;
      for (int i = 0; i < n; ++i) {
        double rs = 0.0;
        for (int j = 0; j < n; ++j) rs += fabs(th * X[i * n + j]);
        mx = fmax(mx, rs);
      }
      int s = 0;
      while (mx > 0.25) { mx *= 0.5; ++s; }
      sS = s;
    }
    __syncthreads();
    const int sq = sS;
    double ths = th;
    for (int q = 0; q < sq; ++q) ths *= 0.5;
    for (int e = t; e < nn; e += 64) {
      A_[e] = ths * X[e];
      P_[e] = A_[e];
      E[g][e] = ((e / n) == (e % n) ? 1.0 : 0.0) + A_[e];
    }
    __syncthreads();
    for (int k = 2; k <= 14; ++k) {  // Taylor
      for (int e = t; e < nn; e += 64) {
        int i = e / n, j = e % n; double s = 0;
        for (int kk = 0; kk < n; ++kk) s += P_[i*n+kk] * A_[kk*n+j];
        T_[e] = s;
      }
      __syncthreads();
      for (int e = t; e < nn; e += 64) { P_[e] = T_[e] / (double)k; E[g][e] += P_[e]; }
      __syncthreads();
    }
    for (int q = 0; q < sq; ++q) {  // squaring
      for (int e = t; e < nn; e += 64) {
        int i = e / n, j = e % n; double s = 0;
        for (int kk = 0; kk < n; ++kk) s += E[g][i*n+kk] * E[g][kk*n+j];
        T_[e] = s;
      }
      __syncthreads();
      for (int e = t; e < nn; e += 64) E[g][e] = T_[e];
      __syncthreads();
    }
  }
  // D = Ea @ Eb @ Eg
  for (int e = t; e < nn; e += 64) {
    int i = e / n, j = e % n; double s = 0;
    for (int k = 0; k < n; ++k) s += E[0][i*n+k] * E[1][k*n+j];
    M1[e] = s;
  }
  __syncthreads();
  for (int e = t; e < nn; e += 64) {
    int i = e / n, j = e % n; double s = 0;
    for (int k = 0; k < n; ++k) s += M1[i*n+k] * E[2][k*n+j];
    ws[b * 165 + c_loff[l] + e] = (float)s;
  }
}

// ---------------- fused main kernel: gauss blocks [0,3072) + feat blocks [3072,4096) ----------------
__global__ __launch_bounds__(256) void main_kernel(
    const float* __restrict__ extr,
    const float* __restrict__ coords,
    const float* __restrict__ depths,
    const float* __restrict__ opac,
    const float* __restrict__ rg,
    const float* __restrict__ gf,
    const float* __restrict__ ws,
    float* __restrict__ out)
{
  __shared__ __align__(16) float smem[11584];
  const int t = threadIdx.x;

  if (blockIdx.x >= NGB) {
    // ---- features transpose-broadcast ----
    float* tile = smem;              // 64*65 floats
    const int blk = blockIdx.x - NGB;
    const int b = blk >> 8;
    const int hw0 = (blk & 255) << 6;
    const int tx = t & 63, ty = t >> 6;
    const float* src = gf + (size_t)b * 64 * 16384 + hw0;
#pragma unroll
    for (int i = 0; i < 16; ++i) {
      int c = i * 4 + ty;
      tile[c * 65 + tx] = src[(size_t)c * 16384 + tx];
    }
    __syncthreads();
    float* dst = out + OFF_FEAT + ((size_t)(b * 16384 + hw0)) * 3 * 64;
    for (int r = ty; r < 192; r += 4) {
      int hw = r / 3;
      dst[(size_t)r * 64 + tx] = tile[tx * 65 + hw];
    }
    return;
  }

  // ---- per-gaussian path ----
  float* sIn    = smem;            // 64*83 = 5312
  float* sSh    = smem + 5312;     // 64*75 = 4800 (16B-aligned: 5312*4 % 16 == 0)
  float* sSmall = smem + 10112;    // 1280: means[0,192) cov[192,768) scl[768,960) rot[960,1216) op[1216,1280)
  float* sD     = smem + 11392;    // 165
  float* sKinv  = smem + 11557;    // 9
  float* sRc    = smem + 11566;    // 9
  float* sOrig  = smem + 11575;    // 3
  float* sMult  = smem + 11578;    // 1

  const int g0 = blockIdx.x * 64;
  const int b  = g0 / HWSPP;

  if (t < 165) sD[t] = ws[b * 165 + t];
  else if (t < 174) sKinv[t - 165] = ws[660 + b * 9 + (t - 165)];
  else if (t < 183) { int k = t - 174; sRc[k] = extr[b * 16 + (k / 3) * 4 + (k % 3)]; }
  else if (t < 186) sOrig[t - 183] = extr[b * 16 + (t - 183) * 4 + 3];
  else if (t == 186) sMult[0] = ws[696 + b];

  {
    const float4* src4 = (const float4*)(rg + (size_t)g0 * RGF);
    for (int idx = t; idx < (64 * RGF) / 4; idx += 256) {
      float4 v = src4[idx];
      int base = idx * 4;
      int gg = base / RGF;
      int ff = base - gg * RGF;
      float vv[4] = {v.x, v.y, v.z, v.w};
#pragma unroll
      for (int e = 0; e < 4; ++e) {
        int g2 = gg, f2 = ff + e;
        if (f2 >= RGF) { g2 += 1; f2 -= RGF; }
        sIn[g2 * RGS + f2] = vv[e];
      }
    }
  }
  __syncthreads();

  if (t < 64) {
    const int gidx = g0 + t;
    const float* q = &sIn[t * RGS];
    const float dpt = depths[gidx];
    const float mlt = sMult[0];
    float sc0 = (0.5f + 14.5f * sigmoidf_(q[0])) * dpt * mlt;
    float sc1 = (0.5f + 14.5f * sigmoidf_(q[1])) * dpt * mlt;
    float sc2 = (0.5f + 14.5f * sigmoidf_(q[2])) * dpt * mlt;
    float r0 = q[3], r1 = q[4], r2 = q[5], r3 = q[6];
    float nr = sqrtf(r0*r0 + r1*r1 + r2*r2 + r3*r3) + 1e-8f;
    float qr = r0/nr, qi = r1/nr, qj = r2/nr, qk = r3/nr;
    float s2 = 2.0f / (qr*qr + qi*qi + qj*qj + qk*qk);
    float R00 = 1.0f - s2*(qj*qj + qk*qk);
    float R01 = s2*(qi*qj - qk*qr);
    float R02 = s2*(qi*qk + qj*qr);
    float R10 = s2*(qi*qj + qk*qr);
    float R11 = 1.0f - s2*(qi*qi + qk*qk);
    float R12 = s2*(qj*qk - qi*qr);
    float R20 = s2*(qi*qk - qj*qr);
    float R21 = s2*(qj*qk + qi*qr);
    float R22 = 1.0f - s2*(qi*qi + qj*qj);
    float v0 = sc0*sc0, v1 = sc1*sc1, v2 = sc2*sc2;
    float C00 = R00*R00*v0 + R01*R01*v1 + R02*R02*v2;
    float C01 = R00*R10*v0 + R01*R11*v1 + R02*R12*v2;
    float C02 = R00*R20*v0 + R01*R21*v1 + R02*R22*v2;
    float C11 = R10*R10*v0 + R11*R11*v1 + R12*R12*v2;
    float C12 = R10*R20*v0 + R11*R21*v1 + R12*R22*v2;
    float C22 = R20*R20*v0 + R21*R21*v1 + R22*R22*v2;
    float2 cxy = ((const float2*)coords)[gidx];
    float dx = sKinv[0]*cxy.x + sKinv[1]*cxy.y + sKinv[2];
    float dy = sKinv[3]*cxy.x + sKinv[4]*cxy.y + sKinv[5];
    float dz = sKinv[6]*cxy.x + sKinv[7]*cxy.y + sKinv[8];
    float inr = 1.0f / sqrtf(dx*dx + dy*dy + dz*dz);
    dx *= inr; dy *= inr; dz *= inr;
    float wx = sRc[0]*dx + sRc[1]*dy + sRc[2]*dz;
    float wy = sRc[3]*dx + sRc[4]*dy + sRc[5]*dz;
    float wz = sRc[6]*dx + sRc[7]*dy + sRc[8]*dz;
    sSmall[t*3+0] = sOrig[0] + wx * dpt;
    sSmall[t*3+1] = sOrig[1] + wy * dpt;
    sSmall[t*3+2] = sOrig[2] + wz * dpt;
    float* cc = &sSmall[192 + t*9];
    cc[0]=C00; cc[1]=C01; cc[2]=C02; cc[3]=C01; cc[4]=C11; cc[5]=C12; cc[6]=C02; cc[7]=C12; cc[8]=C22;
    float* ss = &sSmall[768 + t*3]; ss[0]=sc0; ss[1]=sc1; ss[2]=sc2;
    float* rr = &sSmall[960 + t*4]; rr[0]=qr; rr[1]=qi; rr[2]=qj; rr[3]=qk;
    sSmall[1216 + t] = opac[gidx];
  } else {
    const int task = t - 64;        // 0..191
    const int gg = task & 63;
    const int ch = task >> 6;       // 0..2 (uniform per wave)
    const float* shin = &sIn[gg * RGS + 7 + ch * 25];
    float* shout = &sSh[gg * 75 + ch * 25];
    float in_[25];
#pragma unroll
    for (int j = 0; j < 25; ++j) in_[j] = shin[j];
    shout[0] = sD[0] * in_[0];
#pragma unroll
    for (int i = 0; i < 3; ++i) {
      float a = sD[1+i*3]*in_[1] + sD[1+i*3+1]*in_[2] + sD[1+i*3+2]*in_[3];
      shout[1 + i] = (float)(0.1 * 0.25) * a;
    }
#pragma unroll
    for (int i = 0; i < 5; ++i) {
      float a = 0.f;
#pragma unroll
      for (int j = 0; j < 5; ++j) a += sD[10 + i*5 + j] * in_[4 + j];
      shout[4 + i] = (float)(0.1 * 0.0625) * a;
    }
#pragma unroll
    for (int i = 0; i < 7; ++i) {
      float a = 0.f;
#pragma unroll
      for (int j = 0; j < 7; ++j) a += sD[35 + i*7 + j] * in_[9 + j];
      shout[9 + i] = (float)(0.1 * 0.015625) * a;
    }
#pragma unroll
    for (int i = 0; i < 9; ++i) {
      float a = 0.f;
#pragma unroll
      for (int j = 0; j < 9; ++j) a += sD[84 + i*9 + j] * in_[16 + j];
      shout[16 + i] = (float)(0.1 * 0.00390625) * a;
    }
  }
  __syncthreads();

  {
    float4* osh = (float4*)(out + OFF_SH + (size_t)g0 * 75);
    const float4* s4 = (const float4*)sSh;
    for (int idx = t; idx < 1200; idx += 256) osh[idx] = s4[idx];
    float* om  = out + OFF_MEANS + (size_t)g0 * 3;
    float* oc  = out + OFF_COV   + (size_t)g0 * 9;
    float* os  = out + OFF_SCL   + (size_t)g0 * 3;
    float* orr = out + OFF_ROT   + (size_t)g0 * 4;
    float* oo  = out + OFF_OP    + (size_t)g0;
    if (t < 192) { om[t] = sSmall[t]; os[t] = sSmall[768 + t]; }
    for (int idx = t; idx < 576; idx += 256) oc[idx] = sSmall[192 + idx];
    orr[t] = sSmall[960 + t];
    if (t < 64) oo[t] = sSmall[1216 + t];
  }
}

extern "C" void kernel_launch(void* const* d_in, const int* in_sizes, int n_in,
                              void* d_out, int out_size, void* d_ws, size_t ws_size,
                              hipStream_t stream)
{
  const float* extr   = (const float*)d_in[0];
  const float* intr   = (const float*)d_in[1];
  const float* coords = (const float*)d_in[2];
  const float* depths = (const float*)d_in[3];
  const float* opac   = (const float*)d_in[4];
  const float* rg     = (const float*)d_in[5];
  const float* gf     = (const float*)d_in[6];
  const int*   ih     = (const int*)d_in[7];
  const int*   iw     = (const int*)d_in[8];
  float* out = (float*)d_out;
  float* ws  = (float*)d_ws;

  hipLaunchKernelGGL(setup_kernel, dim3(20), dim3(64), 0, stream, extr, intr, ih, iw, ws);
  hipLaunchKernelGGL(main_kernel, dim3(NGB + NFB), dim3(256), 0, stream,
                     extr, coords, depths, opac, rg, gf, ws, out);
}

// Round 3
// 243.766 us; speedup vs baseline: 1.1803x; 1.1803x over previous
//
#include <hip/hip_runtime.h>
#include <math.h>

#define N_TOT   196608      // B*HW*SPP = 4*16384*3
#define HWSPP   49152       // 16384*3
#define RGF     82          // floats per raw gaussian
#define RGS     83          // padded LDS stride
#define NGB     3072        // gauss blocks
#define NFB     1024        // feat blocks

#define OFF_MEANS 0
#define OFF_COV   589824
#define OFF_SH    2359296
#define OFF_OP    17104896
#define OFF_FEAT  17301504
#define OFF_SCL   29884416
#define OFF_ROT   30474240

// workspace float layout: [0,660) D matrices (b*165 + loff[l]); [660,696) Kinv b*9; [696,700) multiplier
__device__ __constant__ int c_loff[5] = {0, 1, 10, 35, 84};

__device__ __forceinline__ float sigmoidf_(float x) { return 1.0f / (1.0f + expf(-x)); }

// ---------------- setup: angles + Wigner D. One wave per (b,l). ----------------
// Ea = exp(alpha*X1) and Eg = exp(gamma*X1) are CLOSED FORM (X1 couples only (i, 2l-i) pairs):
//   Ea[i,i] = cos(alpha*u_i), Ea[i,2l-i] = sin(alpha*u_i), u_i = X1[i][2l-i]  (u_l = 0).
// Only exp(-beta*X0) is numeric: scaling s=6 + Taylor N=12, register accumulator,
// ping-pong LDS buffers -> 1 barrier per matmul stage (~23 barriers total vs ~115 in R2).
__global__ __launch_bounds__(64) void setup_kernel(
    const float* __restrict__ extr, const float* __restrict__ intr,
    const int* __restrict__ img_h, const int* __restrict__ img_w,
    float* __restrict__ ws)
{
  const int b = blockIdx.x / 5;
  const int l = blockIdx.x % 5;
  const int n = 2 * l + 1;
  const int nn = n * n;
  const int t = threadIdx.x;

  __shared__ double Qr[81], Qi[81], X0c[81];
  __shared__ double X0r[81], U[9];
  __shared__ double A_[81], P0[81], P1[81], E0[81], E1[81];

  // ---- per-lane redundant: Euler angles (fp64, no barriers/broadcast needed) ----
  const float* Ex = extr + b * 16;
  double R00 = Ex[0], R01 = Ex[1], R02 = Ex[2];
  double R11 = Ex[5];
  double R20 = Ex[8], R21 = Ex[9], R22 = Ex[10];
  double x0 = R01, x1 = R11, x2 = R21;
  double nr = sqrt(x0 * x0 + x1 * x1 + x2 * x2);
  x0 /= nr; x1 /= nr; x2 /= nr;
  double beta  = acos(fmin(1.0, fmax(-1.0, x1)));
  double alpha = atan2(x0, x2);
  double ca_ = cos(alpha), sa_ = sin(alpha);
  double gamma = atan2(ca_ * R02 - sa_ * R22, ca_ * R00 - sa_ * R20);

  if (l == 0 && t == 0) {
    const float* K = intr + b * 9;
    double k00=K[0],k01=K[1],k02=K[2],k10=K[3],k11=K[4],k12=K[5],k20=K[6],k21=K[7],k22=K[8];
    double det = k00*(k11*k22-k12*k21) - k01*(k10*k22-k12*k20) + k02*(k10*k21-k11*k20);
    double id = 1.0 / det;
    float* kv = ws + 660 + b * 9;
    kv[0] = (float)((k11*k22-k12*k21)*id);
    kv[1] = (float)((k02*k21-k01*k22)*id);
    kv[2] = (float)((k01*k12-k02*k11)*id);
    kv[3] = (float)((k12*k20-k10*k22)*id);
    kv[4] = (float)((k00*k22-k02*k20)*id);
    kv[5] = (float)((k02*k10-k00*k12)*id);
    kv[6] = (float)((k10*k21-k11*k20)*id);
    kv[7] = (float)((k01*k20-k00*k21)*id);
    kv[8] = (float)((k00*k11-k01*k10)*id);
    double d2 = k00 * k11 - k01 * k10;
    double ps0 = 1.0 / (double)img_w[0];
    double ps1 = 1.0 / (double)img_h[0];
    double sum = (k11 * ps0 - k01 * ps1 - k10 * ps0 + k00 * ps1) / d2;
    ws[696 + b] = (float)(0.1 * sum);
  }

  // ---- build Q (complex) and X0 (complex-basis, real antisymmetric) ----
  for (int e = t; e < 81; e += 64) { Qr[e] = 0.0; Qi[e] = 0.0; X0c[e] = 0.0; }
  __syncthreads();
  if (t == 0) {
    const double irt2 = 0.70710678118654752440;
    for (int m = -l; m < 0; ++m) {
      Qr[(l + m) * n + (l - m)] = irt2;      // q[l+m, l+|m|] = 1/sqrt2
      Qi[(l + m) * n + (l + m)] = -irt2;     // q[l+m, l-|m|] = -i/sqrt2
    }
    Qr[l * n + l] = 1.0;
    for (int m = 1; m <= l; ++m) {
      double sg = (m & 1) ? -1.0 : 1.0;
      Qr[(l + m) * n + (l + m)] = sg * irt2; // (-1)^m/sqrt2
      Qi[(l + m) * n + (l - m)] = sg * irt2; // i(-1)^m/sqrt2
    }
    for (int i = 0; i < n - 1; ++i) {        // X0 = 0.5*(raising+lowering)
      double mi = (double)(-l + i);
      double ci = sqrt((double)(l * (l + 1)) - mi * (mi + 1.0));
      X0c[i * n + (i + 1)] = 0.5 * ci;
      X0c[(i + 1) * n + i] = -0.5 * ci;
    }
  }
  __syncthreads();
  // T = X0c @ Q (P0=Re, P1=Im as temps)
  for (int e = t; e < nn; e += 64) {
    int i = e / n, j = e % n; double s = 0, s2 = 0;
    for (int k = 0; k < n; ++k) { s += X0c[i*n+k]*Qr[k*n+j]; s2 += X0c[i*n+k]*Qi[k*n+j]; }
    P0[e] = s; P1[e] = s2;
  }
  __syncthreads();
  // X0r = Re(Q^H T); U[i] = X1r[i, 2l-i] (the only nonzeros of X1 in the real basis)
  for (int e = t; e < nn; e += 64) {
    int a = e / n, c = e % n; double s = 0;
    for (int r = 0; r < n; ++r) s += Qr[r*n+a]*P0[r*n+c] + Qi[r*n+a]*P1[r*n+c];
    X0r[e] = s;
  }
  if (t < n) {
    int i = t, j = 2 * l - i; double s1 = 0;
    for (int r = 0; r < n; ++r) {
      double mr = (double)(r - l);
      s1 += mr * (Qi[r*n+i]*Qr[r*n+j] - Qr[r*n+i]*Qi[r*n+j]);
    }
    U[i] = s1;
  }
  __syncthreads();

  // ---- exp(-beta*X0): fixed s=6, Taylor N=12; E accumulated in registers ----
  const double ths = -beta / 64.0;           // |ths*X0| <= pi*4.47/64 = 0.22
  for (int e = t; e < nn; e += 64) { A_[e] = ths * X0r[e]; P0[e] = A_[e]; }
  double Ereg[2];
  {
    int ii = 0;
    for (int e = t; e < nn; e += 64) { Ereg[ii++] = ((e/n)==(e%n) ? 1.0 : 0.0) + ths * X0r[e]; }
  }
  __syncthreads();
  double* Pc = P0; double* Pn = P1;
  for (int k = 2; k <= 12; ++k) {
    int ii = 0;
    for (int e = t; e < nn; e += 64) {
      int i = e / n, j = e % n; double s = 0;
      for (int kk = 0; kk < n; ++kk) s += Pc[i*n+kk] * A_[kk*n+j];
      s /= (double)k;
      Pn[e] = s; Ereg[ii++] += s;
    }
    __syncthreads();
    double* tmp = Pc; Pc = Pn; Pn = tmp;
  }
  {
    int ii = 0;
    for (int e = t; e < nn; e += 64) E0[e] = Ereg[ii++];
  }
  __syncthreads();
  double* Es = E0; double* Ed = E1;
  for (int q = 0; q < 6; ++q) {              // d = E^64
    for (int e = t; e < nn; e += 64) {
      int i = e / n, j = e % n; double s = 0;
      for (int kk = 0; kk < n; ++kk) s += Es[i*n+kk] * Es[kk*n+j];
      Ed[e] = s;
    }
    __syncthreads();
    double* tmp = Es; Es = Ed; Ed = tmp;
  }

  // ---- D = Ea * d * Eg, closed-form Ea/Eg (4 LDS reads + 4 trig per element) ----
  for (int e = t; e < nn; e += 64) {
    int i = e / n, j = e % n;
    int i2 = 2 * l - i, j2 = 2 * l - j;
    double cai = cos(alpha * U[i]), sai = sin(alpha * U[i]);
    double cgj = cos(gamma * U[j]), sgj = sin(gamma * U[j]);
    double w1 = cgj * Es[i *n + j] - sgj * Es[i *n + j2];
    double w2 = cgj * Es[i2*n + j] - sgj * Es[i2*n + j2];
    ws[b * 165 + c_loff[l] + e] = (float)(cai * w1 + sai * w2);
  }
}

// ---------------- fused main kernel: gauss blocks [0,3072) + feat blocks [3072,4096) ----------------
__global__ __launch_bounds__(256) void main_kernel(
    const float* __restrict__ extr,
    const float* __restrict__ coords,
    const float* __restrict__ depths,
    const float* __restrict__ opac,
    const float* __restrict__ rg,
    const float* __restrict__ gf,
    const float* __restrict__ ws,
    float* __restrict__ out)
{
  __shared__ __align__(16) float smem[11584];
  const int t = threadIdx.x;

  if (blockIdx.x >= NGB) {
    // ---- features transpose-broadcast ----
    float* tile = smem;              // 64*65 floats
    const int blk = blockIdx.x - NGB;
    const int b = blk >> 8;
    const int hw0 = (blk & 255) << 6;
    const int tx = t & 63, ty = t >> 6;
    const float* src = gf + (size_t)b * 64 * 16384 + hw0;
#pragma unroll
    for (int i = 0; i < 16; ++i) {
      int c = i * 4 + ty;
      tile[c * 65 + tx] = src[(size_t)c * 16384 + tx];
    }
    __syncthreads();
    float* dst = out + OFF_FEAT + ((size_t)(b * 16384 + hw0)) * 3 * 64;
    for (int r = ty; r < 192; r += 4) {
      int hw = r / 3;
      dst[(size_t)r * 64 + tx] = tile[tx * 65 + hw];
    }
    return;
  }

  // ---- per-gaussian path ----
  float* sIn    = smem;            // 64*83 = 5312
  float* sSh    = smem + 5312;     // 64*75 = 4800 (16B-aligned)
  float* sSmall = smem + 10112;    // 1280: means[0,192) cov[192,768) scl[768,960) rot[960,1216) op[1216,1280)
  float* sD     = smem + 11392;    // 165
  float* sKinv  = smem + 11557;    // 9
  float* sRc    = smem + 11566;    // 9
  float* sOrig  = smem + 11575;    // 3
  float* sMult  = smem + 11578;    // 1

  const int g0 = blockIdx.x * 64;
  const int b  = g0 / HWSPP;

  if (t < 165) sD[t] = ws[b * 165 + t];
  else if (t < 174) sKinv[t - 165] = ws[660 + b * 9 + (t - 165)];
  else if (t < 183) { int k = t - 174; sRc[k] = extr[b * 16 + (k / 3) * 4 + (k % 3)]; }
  else if (t < 186) sOrig[t - 183] = extr[b * 16 + (t - 183) * 4 + 3];
  else if (t == 186) sMult[0] = ws[696 + b];

  {
    const float4* src4 = (const float4*)(rg + (size_t)g0 * RGF);
    for (int idx = t; idx < (64 * RGF) / 4; idx += 256) {
      float4 v = src4[idx];
      int base = idx * 4;
      int gg = base / RGF;
      int ff = base - gg * RGF;
      float vv[4] = {v.x, v.y, v.z, v.w};
#pragma unroll
      for (int e = 0; e < 4; ++e) {
        int g2 = gg, f2 = ff + e;
        if (f2 >= RGF) { g2 += 1; f2 -= RGF; }
        sIn[g2 * RGS + f2] = vv[e];
      }
    }
  }
  __syncthreads();

  if (t < 64) {
    const int gidx = g0 + t;
    const float* q = &sIn[t * RGS];
    const float dpt = depths[gidx];
    const float mlt = sMult[0];
    float sc0 = (0.5f + 14.5f * sigmoidf_(q[0])) * dpt * mlt;
    float sc1 = (0.5f + 14.5f * sigmoidf_(q[1])) * dpt * mlt;
    float sc2 = (0.5f + 14.5f * sigmoidf_(q[2])) * dpt * mlt;
    float r0 = q[3], r1 = q[4], r2 = q[5], r3 = q[6];
    float nr = sqrtf(r0*r0 + r1*r1 + r2*r2 + r3*r3) + 1e-8f;
    float qr = r0/nr, qi = r1/nr, qj = r2/nr, qk = r3/nr;
    float s2 = 2.0f / (qr*qr + qi*qi + qj*qj + qk*qk);
    float R00 = 1.0f - s2*(qj*qj + qk*qk);
    float R01 = s2*(qi*qj - qk*qr);
    float R02 = s2*(qi*qk + qj*qr);
    float R10 = s2*(qi*qj + qk*qr);
    float R11 = 1.0f - s2*(qi*qi + qk*qk);
    float R12 = s2*(qj*qk - qi*qr);
    float R20 = s2*(qi*qk - qj*qr);
    float R21 = s2*(qj*qk + qi*qr);
    float R22 = 1.0f - s2*(qi*qi + qj*qj);
    float v0 = sc0*sc0, v1 = sc1*sc1, v2 = sc2*sc2;
    float C00 = R00*R00*v0 + R01*R01*v1 + R02*R02*v2;
    float C01 = R00*R10*v0 + R01*R11*v1 + R02*R12*v2;
    float C02 = R00*R20*v0 + R01*R21*v1 + R02*R22*v2;
    float C11 = R10*R10*v0 + R11*R11*v1 + R12*R12*v2;
    float C12 = R10*R20*v0 + R11*R21*v1 + R12*R22*v2;
    float C22 = R20*R20*v0 + R21*R21*v1 + R22*R22*v2;
    float2 cxy = ((const float2*)coords)[gidx];
    float dx = sKinv[0]*cxy.x + sKinv[1]*cxy.y + sKinv[2];
    float dy = sKinv[3]*cxy.x + sKinv[4]*cxy.y + sKinv[5];
    float dz = sKinv[6]*cxy.x + sKinv[7]*cxy.y + sKinv[8];
    float inr = 1.0f / sqrtf(dx*dx + dy*dy + dz*dz);
    dx *= inr; dy *= inr; dz *= inr;
    float wx = sRc[0]*dx + sRc[1]*dy + sRc[2]*dz;
    float wy = sRc[3]*dx + sRc[4]*dy + sRc[5]*dz;
    float wz = sRc[6]*dx + sRc[7]*dy + sRc[8]*dz;
    sSmall[t*3+0] = sOrig[0] + wx * dpt;
    sSmall[t*3+1] = sOrig[1] + wy * dpt;
    sSmall[t*3+2] = sOrig[2] + wz * dpt;
    float* cc = &sSmall[192 + t*9];
    cc[0]=C00; cc[1]=C01; cc[2]=C02; cc[3]=C01; cc[4]=C11; cc[5]=C12; cc[6]=C02; cc[7]=C12; cc[8]=C22;
    float* ss = &sSmall[768 + t*3]; ss[0]=sc0; ss[1]=sc1; ss[2]=sc2;
    float* rr = &sSmall[960 + t*4]; rr[0]=qr; rr[1]=qi; rr[2]=qj; rr[3]=qk;
    sSmall[1216 + t] = opac[gidx];
  } else {
    const int task = t - 64;        // 0..191
    const int gg = task & 63;
    const int ch = task >> 6;       // 0..2 (uniform per wave)
    const float* shin = &sIn[gg * RGS + 7 + ch * 25];
    float* shout = &sSh[gg * 75 + ch * 25];
    float in_[25];
#pragma unroll
    for (int j = 0; j < 25; ++j) in_[j] = shin[j];
    shout[0] = sD[0] * in_[0];
#pragma unroll
    for (int i = 0; i < 3; ++i) {
      float a = sD[1+i*3]*in_[1] + sD[1+i*3+1]*in_[2] + sD[1+i*3+2]*in_[3];
      shout[1 + i] = (float)(0.1 * 0.25) * a;
    }
#pragma unroll
    for (int i = 0; i < 5; ++i) {
      float a = 0.f;
#pragma unroll
      for (int j = 0; j < 5; ++j) a += sD[10 + i*5 + j] * in_[4 + j];
      shout[4 + i] = (float)(0.1 * 0.0625) * a;
    }
#pragma unroll
    for (int i = 0; i < 7; ++i) {
      float a = 0.f;
#pragma unroll
      for (int j = 0; j < 7; ++j) a += sD[35 + i*7 + j] * in_[9 + j];
      shout[9 + i] = (float)(0.1 * 0.015625) * a;
    }
#pragma unroll
    for (int i = 0; i < 9; ++i) {
      float a = 0.f;
#pragma unroll
      for (int j = 0; j < 9; ++j) a += sD[84 + i*9 + j] * in_[16 + j];
      shout[16 + i] = (float)(0.1 * 0.00390625) * a;
    }
  }
  __syncthreads();

  {
    float4* osh = (float4*)(out + OFF_SH + (size_t)g0 * 75);
    const float4* s4 = (const float4*)sSh;
    for (int idx = t; idx < 1200; idx += 256) osh[idx] = s4[idx];
    float* om  = out + OFF_MEANS + (size_t)g0 * 3;
    float* oc  = out + OFF_COV   + (size_t)g0 * 9;
    float* os  = out + OFF_SCL   + (size_t)g0 * 3;
    float* orr = out + OFF_ROT   + (size_t)g0 * 4;
    float* oo  = out + OFF_OP    + (size_t)g0;
    if (t < 192) { om[t] = sSmall[t]; os[t] = sSmall[768 + t]; }
    for (int idx = t; idx < 576; idx += 256) oc[idx] = sSmall[192 + idx];
    orr[t] = sSmall[960 + t];
    if (t < 64) oo[t] = sSmall[1216 + t];
  }
}

extern "C" void kernel_launch(void* const* d_in, const int* in_sizes, int n_in,
                              void* d_out, int out_size, void* d_ws, size_t ws_size,
                              hipStream_t stream)
{
  const float* extr   = (const float*)d_in[0];
  const float* intr   = (const float*)d_in[1];
  const float* coords = (const float*)d_in[2];
  const float* depths = (const float*)d_in[3];
  const float* opac   = (const float*)d_in[4];
  const float* rg     = (const float*)d_in[5];
  const float* gf     = (const float*)d_in[6];
  const int*   ih     = (const int*)d_in[7];
  const int*   iw     = (const int*)d_in[8];
  float* out = (float*)d_out;
  float* ws  = (float*)d_ws;

  hipLaunchKernelGGL(setup_kernel, dim3(20), dim3(64), 0, stream, extr, intr, ih, iw, ws);
  hipLaunchKernelGGL(main_kernel, dim3(NGB + NFB), dim3(256), 0, stream,
                     extr, coords, depths, opac, rg, gf, ws, out);
}

// Round 4
// 236.932 us; speedup vs baseline: 1.2144x; 1.0288x over previous
//
#include <hip/hip_runtime.h>
#include <math.h>

#define N_TOT   196608      // B*HW*SPP = 4*16384*3
#define HWSPP   49152       // 16384*3
#define RGF     82          // floats per raw gaussian
#define RGS     83          // padded LDS stride
#define NGB     3072        // gauss blocks
#define NFB     1024        // feat blocks

#define OFF_MEANS 0
#define OFF_COV   589824
#define OFF_SH    2359296
#define OFF_OP    17104896
#define OFF_FEAT  17301504
#define OFF_SCL   29884416
#define OFF_ROT   30474240

// workspace float layout: [0,660) D matrices (b*165 + loff[l]); [660,696) Kinv b*9; [696,700) multiplier
__device__ __constant__ int c_loff[5] = {0, 1, 10, 35, 84};

__device__ __forceinline__ float sigmoidf_(float x) { return 1.0f / (1.0f + expf(-x)); }

// ---------------- setup: angles + Wigner D. One wave per (b,l). (unchanged from R3) ----------------
__global__ __launch_bounds__(64) void setup_kernel(
    const float* __restrict__ extr, const float* __restrict__ intr,
    const int* __restrict__ img_h, const int* __restrict__ img_w,
    float* __restrict__ ws)
{
  const int b = blockIdx.x / 5;
  const int l = blockIdx.x % 5;
  const int n = 2 * l + 1;
  const int nn = n * n;
  const int t = threadIdx.x;

  __shared__ double Qr[81], Qi[81], X0c[81];
  __shared__ double X0r[81], U[9];
  __shared__ double A_[81], P0[81], P1[81], E0[81], E1[81];

  const float* Ex = extr + b * 16;
  double R00 = Ex[0], R01 = Ex[1], R02 = Ex[2];
  double R11 = Ex[5];
  double R20 = Ex[8], R21 = Ex[9], R22 = Ex[10];
  double x0 = R01, x1 = R11, x2 = R21;
  double nr = sqrt(x0 * x0 + x1 * x1 + x2 * x2);
  x0 /= nr; x1 /= nr; x2 /= nr;
  double beta  = acos(fmin(1.0, fmax(-1.0, x1)));
  double alpha = atan2(x0, x2);
  double ca_ = cos(alpha), sa_ = sin(alpha);
  double gamma = atan2(ca_ * R02 - sa_ * R22, ca_ * R00 - sa_ * R20);

  if (l == 0 && t == 0) {
    const float* K = intr + b * 9;
    double k00=K[0],k01=K[1],k02=K[2],k10=K[3],k11=K[4],k12=K[5],k20=K[6],k21=K[7],k22=K[8];
    double det = k00*(k11*k22-k12*k21) - k01*(k10*k22-k12*k20) + k02*(k10*k21-k11*k20);
    double id = 1.0 / det;
    float* kv = ws + 660 + b * 9;
    kv[0] = (float)((k11*k22-k12*k21)*id);
    kv[1] = (float)((k02*k21-k01*k22)*id);
    kv[2] = (float)((k01*k12-k02*k11)*id);
    kv[3] = (float)((k12*k20-k10*k22)*id);
    kv[4] = (float)((k00*k22-k02*k20)*id);
    kv[5] = (float)((k02*k10-k00*k12)*id);
    kv[6] = (float)((k10*k21-k11*k20)*id);
    kv[7] = (float)((k01*k20-k00*k21)*id);
    kv[8] = (float)((k00*k11-k01*k10)*id);
    double d2 = k00 * k11 - k01 * k10;
    double ps0 = 1.0 / (double)img_w[0];
    double ps1 = 1.0 / (double)img_h[0];
    double sum = (k11 * ps0 - k01 * ps1 - k10 * ps0 + k00 * ps1) / d2;
    ws[696 + b] = (float)(0.1 * sum);
  }

  for (int e = t; e < 81; e += 64) { Qr[e] = 0.0; Qi[e] = 0.0; X0c[e] = 0.0; }
  __syncthreads();
  if (t == 0) {
    const double irt2 = 0.70710678118654752440;
    for (int m = -l; m < 0; ++m) {
      Qr[(l + m) * n + (l - m)] = irt2;
      Qi[(l + m) * n + (l + m)] = -irt2;
    }
    Qr[l * n + l] = 1.0;
    for (int m = 1; m <= l; ++m) {
      double sg = (m & 1) ? -1.0 : 1.0;
      Qr[(l + m) * n + (l + m)] = sg * irt2;
      Qi[(l + m) * n + (l - m)] = sg * irt2;
    }
    for (int i = 0; i < n - 1; ++i) {
      double mi = (double)(-l + i);
      double ci = sqrt((double)(l * (l + 1)) - mi * (mi + 1.0));
      X0c[i * n + (i + 1)] = 0.5 * ci;
      X0c[(i + 1) * n + i] = -0.5 * ci;
    }
  }
  __syncthreads();
  for (int e = t; e < nn; e += 64) {
    int i = e / n, j = e % n; double s = 0, s2 = 0;
    for (int k = 0; k < n; ++k) { s += X0c[i*n+k]*Qr[k*n+j]; s2 += X0c[i*n+k]*Qi[k*n+j]; }
    P0[e] = s; P1[e] = s2;
  }
  __syncthreads();
  for (int e = t; e < nn; e += 64) {
    int a = e / n, c = e % n; double s = 0;
    for (int r = 0; r < n; ++r) s += Qr[r*n+a]*P0[r*n+c] + Qi[r*n+a]*P1[r*n+c];
    X0r[e] = s;
  }
  if (t < n) {
    int i = t, j = 2 * l - i; double s1 = 0;
    for (int r = 0; r < n; ++r) {
      double mr = (double)(r - l);
      s1 += mr * (Qi[r*n+i]*Qr[r*n+j] - Qr[r*n+i]*Qi[r*n+j]);
    }
    U[i] = s1;
  }
  __syncthreads();

  const double ths = -beta / 64.0;
  for (int e = t; e < nn; e += 64) { A_[e] = ths * X0r[e]; P0[e] = A_[e]; }
  double Ereg[2];
  {
    int ii = 0;
    for (int e = t; e < nn; e += 64) { Ereg[ii++] = ((e/n)==(e%n) ? 1.0 : 0.0) + ths * X0r[e]; }
  }
  __syncthreads();
  double* Pc = P0; double* Pn = P1;
  for (int k = 2; k <= 12; ++k) {
    int ii = 0;
    for (int e = t; e < nn; e += 64) {
      int i = e / n, j = e % n; double s = 0;
      for (int kk = 0; kk < n; ++kk) s += Pc[i*n+kk] * A_[kk*n+j];
      s /= (double)k;
      Pn[e] = s; Ereg[ii++] += s;
    }
    __syncthreads();
    double* tmp = Pc; Pc = Pn; Pn = tmp;
  }
  {
    int ii = 0;
    for (int e = t; e < nn; e += 64) E0[e] = Ereg[ii++];
  }
  __syncthreads();
  double* Es = E0; double* Ed = E1;
  for (int q = 0; q < 6; ++q) {
    for (int e = t; e < nn; e += 64) {
      int i = e / n, j = e % n; double s = 0;
      for (int kk = 0; kk < n; ++kk) s += Es[i*n+kk] * Es[kk*n+j];
      Ed[e] = s;
    }
    __syncthreads();
    double* tmp = Es; Es = Ed; Ed = tmp;
  }

  for (int e = t; e < nn; e += 64) {
    int i = e / n, j = e % n;
    int i2 = 2 * l - i, j2 = 2 * l - j;
    double cai = cos(alpha * U[i]), sai = sin(alpha * U[i]);
    double cgj = cos(gamma * U[j]), sgj = sin(gamma * U[j]);
    double w1 = cgj * Es[i *n + j] - sgj * Es[i *n + j2];
    double w2 = cgj * Es[i2*n + j] - sgj * Es[i2*n + j2];
    ws[b * 165 + c_loff[l] + e] = (float)(cai * w1 + sai * w2);
  }
}

// ---------------- fused main kernel: 4096 blocks; idx%4==3 -> feat, else gauss ----------------
// LDS budget 6784 floats = 26.5 KB -> 6 blocks/CU (was 46.3 KB -> 3). sIn region is
// reused as the SH output staging buffer (inputs read to registers, barrier, overwrite).
__global__ __launch_bounds__(256, 6) void main_kernel(
    const float* __restrict__ extr,
    const float* __restrict__ coords,
    const float* __restrict__ depths,
    const float* __restrict__ opac,
    const float* __restrict__ rg,
    const float* __restrict__ gf,
    const float* __restrict__ ws,
    float* __restrict__ out)
{
  __shared__ __align__(16) float smem[6784];
  const int t = threadIdx.x;
  const int bq = blockIdx.x >> 2;
  const int br = blockIdx.x & 3;

  if (br == 3) {
    // ---- features transpose-broadcast (feat block index bq in [0,1024)) ----
    float* tile = smem;              // 64*65 = 4160 floats
    const int b = bq >> 8;
    const int hw0 = (bq & 255) << 6;
    const int tx = t & 63, ty = t >> 6;
    const float* src = gf + (size_t)b * 64 * 16384 + hw0;
#pragma unroll
    for (int i = 0; i < 16; ++i) {
      int c = i * 4 + ty;
      tile[c * 65 + tx] = src[(size_t)c * 16384 + tx];
    }
    __syncthreads();
    float* dst = out + OFF_FEAT + ((size_t)(b * 16384 + hw0)) * 3 * 64;
    for (int r = ty; r < 192; r += 4) {
      int hw = r / 3;
      dst[(size_t)r * 64 + tx] = tile[tx * 65 + hw];
    }
    return;
  }

  // ---- per-gaussian path (gauss block index gb in [0,3072)) ----
  const int gb = bq * 3 + br;
  float* sIn    = smem;            // 64*83 = 5312; REUSED as SH out staging (64*75, stride 75)
  float* sSmall = smem + 5312;     // 1280: means[0,192) cov[192,768) scl[768,960) rot[960,1216) op[1216,1280)
  float* sD     = smem + 6592;     // 165
  float* sKinv  = smem + 6757;     // 9
  float* sRc    = smem + 6766;     // 9
  float* sOrig  = smem + 6775;     // 3
  float* sMult  = smem + 6778;     // 1

  const int g0 = gb * 64;
  const int b  = g0 / HWSPP;

  // prefetch per-gaussian scalars early (overlap with staging)
  float dpt = 0.f, opc = 0.f;
  float2 cxy = make_float2(0.f, 0.f);
  if (t < 64) {
    const int gidx = g0 + t;
    dpt = depths[gidx];
    opc = opac[gidx];
    cxy = ((const float2*)coords)[gidx];
  }

  if (t < 165) sD[t] = ws[b * 165 + t];
  else if (t < 174) sKinv[t - 165] = ws[660 + b * 9 + (t - 165)];
  else if (t < 183) { int k = t - 174; sRc[k] = extr[b * 16 + (k / 3) * 4 + (k % 3)]; }
  else if (t < 186) sOrig[t - 183] = extr[b * 16 + (t - 183) * 4 + 3];
  else if (t == 186) sMult[0] = ws[696 + b];

  {
    const float4* src4 = (const float4*)(rg + (size_t)g0 * RGF);
    for (int idx = t; idx < (64 * RGF) / 4; idx += 256) {
      float4 v = src4[idx];
      int base = idx * 4;
      int gg = base / RGF;
      int ff = base - gg * RGF;
      float vv[4] = {v.x, v.y, v.z, v.w};
#pragma unroll
      for (int e = 0; e < 4; ++e) {
        int g2 = gg, f2 = ff + e;
        if (f2 >= RGF) { g2 += 1; f2 -= RGF; }
        sIn[g2 * RGS + f2] = vv[e];
      }
    }
  }
  __syncthreads();

  // ---- phase 2a: read LDS inputs into registers ----
  float reg[25];
  int gg = 0, ch = 0;
  if (t < 64) {
    const float* q = &sIn[t * RGS];
#pragma unroll
    for (int j = 0; j < 7; ++j) reg[j] = q[j];
  } else {
    const int task = t - 64;        // 0..191
    gg = task & 63;
    ch = task >> 6;                 // 0..2 (uniform per wave)
    const float* shin = &sIn[gg * RGS + 7 + ch * 25];
#pragma unroll
    for (int j = 0; j < 25; ++j) reg[j] = shin[j];
  }
  __syncthreads();

  // ---- phase 2b: compute; SH outputs overwrite sIn region (stride 75) ----
  if (t < 64) {
    const float mlt = sMult[0];
    float sc0 = (0.5f + 14.5f * sigmoidf_(reg[0])) * dpt * mlt;
    float sc1 = (0.5f + 14.5f * sigmoidf_(reg[1])) * dpt * mlt;
    float sc2 = (0.5f + 14.5f * sigmoidf_(reg[2])) * dpt * mlt;
    float r0 = reg[3], r1 = reg[4], r2 = reg[5], r3 = reg[6];
    float nr = sqrtf(r0*r0 + r1*r1 + r2*r2 + r3*r3) + 1e-8f;
    float qr = r0/nr, qi = r1/nr, qj = r2/nr, qk = r3/nr;
    float s2 = 2.0f / (qr*qr + qi*qi + qj*qj + qk*qk);
    float R00 = 1.0f - s2*(qj*qj + qk*qk);
    float R01 = s2*(qi*qj - qk*qr);
    float R02 = s2*(qi*qk + qj*qr);
    float R10 = s2*(qi*qj + qk*qr);
    float R11 = 1.0f - s2*(qi*qi + qk*qk);
    float R12 = s2*(qj*qk - qi*qr);
    float R20 = s2*(qi*qk - qj*qr);
    float R21 = s2*(qj*qk + qi*qr);
    float R22 = 1.0f - s2*(qi*qi + qj*qj);
    float v0 = sc0*sc0, v1 = sc1*sc1, v2 = sc2*sc2;
    float C00 = R00*R00*v0 + R01*R01*v1 + R02*R02*v2;
    float C01 = R00*R10*v0 + R01*R11*v1 + R02*R12*v2;
    float C02 = R00*R20*v0 + R01*R21*v1 + R02*R22*v2;
    float C11 = R10*R10*v0 + R11*R11*v1 + R12*R12*v2;
    float C12 = R10*R20*v0 + R11*R21*v1 + R12*R22*v2;
    float C22 = R20*R20*v0 + R21*R21*v1 + R22*R22*v2;
    float dx = sKinv[0]*cxy.x + sKinv[1]*cxy.y + sKinv[2];
    float dy = sKinv[3]*cxy.x + sKinv[4]*cxy.y + sKinv[5];
    float dz = sKinv[6]*cxy.x + sKinv[7]*cxy.y + sKinv[8];
    float inr = 1.0f / sqrtf(dx*dx + dy*dy + dz*dz);
    dx *= inr; dy *= inr; dz *= inr;
    float wx = sRc[0]*dx + sRc[1]*dy + sRc[2]*dz;
    float wy = sRc[3]*dx + sRc[4]*dy + sRc[5]*dz;
    float wz = sRc[6]*dx + sRc[7]*dy + sRc[8]*dz;
    sSmall[t*3+0] = sOrig[0] + wx * dpt;
    sSmall[t*3+1] = sOrig[1] + wy * dpt;
    sSmall[t*3+2] = sOrig[2] + wz * dpt;
    float* cc = &sSmall[192 + t*9];
    cc[0]=C00; cc[1]=C01; cc[2]=C02; cc[3]=C01; cc[4]=C11; cc[5]=C12; cc[6]=C02; cc[7]=C12; cc[8]=C22;
    float* ss = &sSmall[768 + t*3]; ss[0]=sc0; ss[1]=sc1; ss[2]=sc2;
    float* rr = &sSmall[960 + t*4]; rr[0]=qr; rr[1]=qi; rr[2]=qj; rr[3]=qk;
    sSmall[1216 + t] = opc;
  } else {
    float* shout = &sIn[gg * 75 + ch * 25];   // overwrite staging region, stride 75
    shout[0] = sD[0] * reg[0];
#pragma unroll
    for (int i = 0; i < 3; ++i) {
      float a = sD[1+i*3]*reg[1] + sD[1+i*3+1]*reg[2] + sD[1+i*3+2]*reg[3];
      shout[1 + i] = (float)(0.1 * 0.25) * a;
    }
#pragma unroll
    for (int i = 0; i < 5; ++i) {
      float a = 0.f;
#pragma unroll
      for (int j = 0; j < 5; ++j) a += sD[10 + i*5 + j] * reg[4 + j];
      shout[4 + i] = (float)(0.1 * 0.0625) * a;
    }
#pragma unroll
    for (int i = 0; i < 7; ++i) {
      float a = 0.f;
#pragma unroll
      for (int j = 0; j < 7; ++j) a += sD[35 + i*7 + j] * reg[9 + j];
      shout[9 + i] = (float)(0.1 * 0.015625) * a;
    }
#pragma unroll
    for (int i = 0; i < 9; ++i) {
      float a = 0.f;
#pragma unroll
      for (int j = 0; j < 9; ++j) a += sD[84 + i*9 + j] * reg[16 + j];
      shout[16 + i] = (float)(0.1 * 0.00390625) * a;
    }
  }
  __syncthreads();

  // ---- phase 3: coalesced global writes ----
  {
    float4* osh = (float4*)(out + OFF_SH + (size_t)g0 * 75);
    const float4* s4 = (const float4*)sIn;    // SH staging now lives here (4800 floats)
    for (int idx = t; idx < 1200; idx += 256) osh[idx] = s4[idx];
    float* om  = out + OFF_MEANS + (size_t)g0 * 3;
    float* oc  = out + OFF_COV   + (size_t)g0 * 9;
    float* os  = out + OFF_SCL   + (size_t)g0 * 3;
    float* orr = out + OFF_ROT   + (size_t)g0 * 4;
    float* oo  = out + OFF_OP    + (size_t)g0;
    if (t < 192) { om[t] = sSmall[t]; os[t] = sSmall[768 + t]; }
    for (int idx = t; idx < 576; idx += 256) oc[idx] = sSmall[192 + idx];
    orr[t] = sSmall[960 + t];
    if (t < 64) oo[t] = sSmall[1216 + t];
  }
}

extern "C" void kernel_launch(void* const* d_in, const int* in_sizes, int n_in,
                              void* d_out, int out_size, void* d_ws, size_t ws_size,
                              hipStream_t stream)
{
  const float* extr   = (const float*)d_in[0];
  const float* intr   = (const float*)d_in[1];
  const float* coords = (const float*)d_in[2];
  const float* depths = (const float*)d_in[3];
  const float* opac   = (const float*)d_in[4];
  const float* rg     = (const float*)d_in[5];
  const float* gf     = (const float*)d_in[6];
  const int*   ih     = (const int*)d_in[7];
  const int*   iw     = (const int*)d_in[8];
  float* out = (float*)d_out;
  float* ws  = (float*)d_ws;

  hipLaunchKernelGGL(setup_kernel, dim3(20), dim3(64), 0, stream, extr, intr, ih, iw, ws);
  hipLaunchKernelGGL(main_kernel, dim3(NGB + NFB), dim3(256), 0, stream,
                     extr, coords, depths, opac, rg, gf, ws, out);
}